// Round 4
// baseline (144.565 us; speedup 1.0000x reference)
//
#include <hip/hip_runtime.h>
#include <hip/hip_bf16.h>

// HeteroLinear fused forward on gfx950: out[i] = x[i] @ W[tv[i]] + b[tv[i]]
// N=131072, IN=OUT=256, T=8, tv sorted. Memory-bound: floor ~256 MB -> ~41 us.
// R4: NO LDS, NO barriers in the main kernel. A-fragments of mfma_16x16x32
// are natively coalesced from row-major x (16 rows x 128B contiguous per
// wave-load), B-fragments from L2-resident pre-transposed bf16 weights.
// 4096 independent blocks x 4 independent waves -> TLP hides all latency.

#define NROWS 131072
#define KD 256
#define ND 256
#define RT 32                      // rows per block
#define NBLK (NROWS / RT)          // 4096

typedef __attribute__((ext_vector_type(8))) short short8;
typedef __attribute__((ext_vector_type(4))) float f32x4;
typedef __attribute__((ext_vector_type(4))) float flt4;

__device__ inline unsigned short f2bf(float f) {
    unsigned int u = __float_as_uint(f);
    u += 0x7FFFu + ((u >> 16) & 1u);   // RNE
    return (unsigned short)(u >> 16);
}

// ---- weight prep: wT[t][n][k] = bf16(w[t][k][n]) ----
// grid = 256 blocks: t = bid>>5, k-chunk of 8 rows = bid&31. 256 threads.
__global__ __launch_bounds__(256) void prep_weights(const float* __restrict__ w,
                                                    unsigned short* __restrict__ wT) {
    __shared__ unsigned short L[8][264];
    const int t  = blockIdx.x >> 5;
    const int k0 = (blockIdx.x & 31) * 8;
    const int tid = threadIdx.x;

    #pragma unroll
    for (int i = 0; i < 2; ++i) {
        int idx = i * 256 + tid;          // 0..511 float4s (8 rows x 64)
        int kr  = idx >> 6;
        int nq  = idx & 63;
        const flt4* src = (const flt4*)(w + ((size_t)t * 256 + k0 + kr) * 256);
        flt4 v = src[nq];
        #pragma unroll
        for (int j = 0; j < 4; ++j) L[kr][nq * 4 + j] = f2bf(v[j]);
    }
    __syncthreads();

    int n = tid;
    short8 v;
    #pragma unroll
    for (int j = 0; j < 8; ++j) v[j] = (short)L[j][n];
    *(short8*)(wT + ((size_t)t * 256 + n) * 256 + k0) = v;
}

// ---- main GEMM: pure streaming, no LDS, no syncthreads ----
__global__ __launch_bounds__(256) void hetero_gemm(
        const float* __restrict__ x, const int* __restrict__ tv,
        const unsigned short* __restrict__ wT, const float* __restrict__ bias,
        float* __restrict__ out) {
    const int tid  = threadIdx.x;
    const int lane = tid & 63;
    const int wv   = tid >> 6;            // wave 0..3 -> cols wv*64..+63
    const int cl   = lane & 15;
    const int kg   = lane >> 4;
    const int r0   = blockIdx.x * RT;

    const int tmin = tv[r0];              // sorted -> block min/max at ends
    const int tmax = tv[r0 + RT - 1];

    // per-lane store-row types (L1-resident)
    int ty[2][4];
    #pragma unroll
    for (int m = 0; m < 2; ++m)
        #pragma unroll
        for (int j = 0; j < 4; ++j)
            ty[m][j] = tv[r0 + m * 16 + kg * 4 + j];

    for (int t = tmin; t <= tmax; ++t) {
        const unsigned short* Bt = wT + (size_t)t * (KD * ND);
        float bv[4];
        #pragma unroll
        for (int n = 0; n < 4; ++n)
            bv[n] = bias[t * ND + wv * 64 + n * 16 + cl];

        f32x4 zero = {0.f, 0.f, 0.f, 0.f};
        f32x4 acc[2][4];
        #pragma unroll
        for (int m = 0; m < 2; ++m)
            #pragma unroll
            for (int n = 0; n < 4; ++n) acc[m][n] = zero;

        #pragma unroll
        for (int ks = 0; ks < 8; ++ks) {
            // A-fragments straight from global x: for fixed m, the wave's 64
            // lanes read rows r0+m*16+cl, bytes k0*4..k0*4+32 -> 16 rows x
            // 128B contiguous = perfectly coalesced.
            short8 a[2];
            #pragma unroll
            for (int m = 0; m < 2; ++m) {
                const float* ap = x + (size_t)(r0 + m * 16 + cl) * KD + ks * 32 + kg * 8;
                f32x4 v0 = *(const f32x4*)ap;
                f32x4 v1 = *(const f32x4*)(ap + 4);
                short8 t8;
                #pragma unroll
                for (int j = 0; j < 4; ++j) {
                    t8[j]     = (short)__bfloat16_as_ushort(__float2bfloat16(v0[j]));
                    t8[4 + j] = (short)__bfloat16_as_ushort(__float2bfloat16(v1[j]));
                }
                a[m] = t8;
            }
            short8 b[4];
            #pragma unroll
            for (int n = 0; n < 4; ++n)
                b[n] = *(const short8*)(Bt + (size_t)(wv * 64 + n * 16 + cl) * KD
                                        + ks * 32 + kg * 8);
            #pragma unroll
            for (int m = 0; m < 2; ++m)
                #pragma unroll
                for (int n = 0; n < 4; ++n)
                    acc[m][n] = __builtin_amdgcn_mfma_f32_16x16x32_bf16(
                        a[m], b[n], acc[m][n], 0, 0, 0);
        }

        // epilogue: bias + predicated nontemporal store (row type == t)
        #pragma unroll
        for (int m = 0; m < 2; ++m) {
            #pragma unroll
            for (int j = 0; j < 4; ++j) {
                if (ty[m][j] == t) {
                    int r = m * 16 + kg * 4 + j;
                    float* orow = out + (size_t)(r0 + r) * ND + wv * 64 + cl;
                    #pragma unroll
                    for (int n = 0; n < 4; ++n)
                        __builtin_nontemporal_store(acc[m][n][j] + bv[n], orow + n * 16);
                }
            }
        }
    }
}

extern "C" void kernel_launch(void* const* d_in, const int* in_sizes, int n_in,
                              void* d_out, int out_size, void* d_ws, size_t ws_size,
                              hipStream_t stream) {
    const float* x    = (const float*)d_in[0];
    const int*   tv   = (const int*)d_in[1];
    const float* w    = (const float*)d_in[2];
    const float* bias = (const float*)d_in[3];
    float* out = (float*)d_out;
    unsigned short* wT = (unsigned short*)d_ws;   // 8*256*256*2 = 1 MiB

    prep_weights<<<dim3(256), dim3(256), 0, stream>>>(w, wT);
    hetero_gemm<<<dim3(NBLK), dim3(256), 0, stream>>>(x, tv, wT, bias, out);
}